// Round 1
// baseline (1953.056 us; speedup 1.0000x reference)
//
#include <hip/hip_runtime.h>
#include <stdint.h>
#include <string.h>

#define DM 256
#define NB 4
#define SEQ 1024
#define NTOK 4096       // NB*SEQ
#define RHID 64
#define DSUM 960        // 64+128+256+512
#define SZ2 348160      // 64^2+128^2+256^2+512^2
#define VOCABN 32000
#define XROWS 6144      // 4 batches * (512 pad + 1024 data)
#define XPADE (XROWS * DSUM)   // elements per padded X array

typedef __attribute__((ext_vector_type(8))) short short8;
typedef __attribute__((ext_vector_type(4))) float floatx4;

__device__ __forceinline__ unsigned short f2bf(float f) {
  unsigned int x = __float_as_uint(f);
  x += 0x7fffu + ((x >> 16) & 1u);
  return (unsigned short)(x >> 16);
}
__device__ __forceinline__ float bf2f(unsigned short u) {
  return __uint_as_float(((unsigned int)u) << 16);
}

// async global->LDS, 16B per lane; lds base must be wave-uniform, lane i lands at base + i*16B
__device__ __forceinline__ void gll16(const unsigned short* g, unsigned short* l) {
  __builtin_amdgcn_global_load_lds((const __attribute__((address_space(1))) void*)g,
                                   (__attribute__((address_space(3))) void*)l, 16, 0, 0);
}

struct Ptr4 { const float* p[4]; };

__device__ __forceinline__ void world_from_id(int id, int& w, int& e) {
  if (id < 4096)        { w = 0; e = id; }
  else if (id < 20480)  { w = 1; e = id - 4096; }
  else if (id < 86016)  { w = 2; e = id - 20480; }
  else                  { w = 3; e = id - 86016; }
}

// ---------------- device-scope grid barrier ----------------
// All blocks of the calling kernel MUST be co-resident (grid <= 256 blocks,
// <=40KB LDS, 4 waves/block -> at most 1 block/CU needed; guaranteed).
// Generation-ticket barrier: counter must start at a multiple of nb (setup zeroes it).
__device__ __forceinline__ void gridbar(unsigned int* cnt, unsigned int nb) {
  __syncthreads();
  if (threadIdx.x == 0) {
    __threadfence();                                  // device-scope release
    unsigned int ticket = atomicAdd(cnt, 1u);         // device-scope by default
    unsigned int target = (ticket / nb + 1u) * nb;
    while (__hip_atomic_load(cnt, __ATOMIC_RELAXED, __HIP_MEMORY_SCOPE_AGENT) < target)
      __builtin_amdgcn_s_sleep(1);
    __threadfence();                                  // device-scope acquire
  }
  __syncthreads();
}

// ---------------- tile maps ----------------

__device__ __forceinline__ void tile22(int t, int& w, int& tm, int& tn) {
  if (t < 16)      { w = 3; tm = t >> 2;        tn = t & 3; }
  else if (t < 20) { w = 2; tm = (t - 16) >> 1; tn = (t - 16) & 1; }
  else if (t == 20){ w = 1; tm = 0;             tn = 0; }
  else             { w = 0; tm = 0;             tn = 0; }
}

__device__ __forceinline__ void tile256(int t, int& w, int& tm, int& tn) {
  if (t < 128)      { w = 3; tm = t >> 2;          tn = t & 3; }
  else if (t < 192) { w = 2; tm = (t - 128) >> 1;  tn = (t - 128) & 1; }
  else if (t < 224) { w = 1; tm = t - 192;         tn = 0; }
  else              { w = 0; tm = t - 224;         tn = 0; }
}

// ---------------- dispatch 1: fused setup ----------------
// block ranges: [0,4096) embed | [4096,5456) prep_M | [5456,6416) prep_B |
// [6416,7440) prep_C | [7440,9440) transpose_ow | [9440,9696) zero pads + sync counters

struct SetupArgs {
  const int* x; const float* emb;
  float* xef; unsigned short* xebf;
  Ptr4 A, B, C;
  const float* ow;
  unsigned short *Mh, *Ml, *MTh, *MTl;
  unsigned short *Bt, *Ct, *owT;
  unsigned short *XAh, *XAl, *XBh, *XBl;
  unsigned int* syncp;
};

__global__ __launch_bounds__(256) void k_setup(SetupArgs a) {
  __shared__ float t[64][65];
  int bid = blockIdx.x, tid = threadIdx.x;
  if (bid < 4096) {                       // embed + bf16 copy
    int tok = a.x[bid];
    float v = a.emb[(size_t)tok * DM + tid];
    a.xef[(size_t)bid * DM + tid] = v;
    a.xebf[(size_t)bid * DM + tid] = f2bf(v);
  } else if (bid < 5456) {                // prep_M (split-bf16 of 0.1*A, + transpose)
    int id = (bid - 4096) * 256 + tid;
    int w, e; world_from_id(id, w, e);
    int s = 6 + w, ds = 64 << w;
    int i = e >> s, j = e & (ds - 1);
    float v = 0.1f * a.A.p[w][e];
    unsigned short h = f2bf(v);
    unsigned short l = f2bf(v - bf2f(h));
    a.Mh[id] = h; a.Ml[id] = l;
    int tix = (id - e) + (j << s) + i;
    a.MTh[tix] = h; a.MTl[tix] = l;
  } else if (bid < 6416) {                // prep_B (concat B^T, bf16)
    int jc = bid - 5456;
    int d = tid;
    int w, j;
    if (jc < 64)       { w = 0; j = jc; }
    else if (jc < 192) { w = 1; j = jc - 64; }
    else if (jc < 448) { w = 2; j = jc - 192; }
    else               { w = 3; j = jc - 448; }
    int ds = 64 << w;
    a.Bt[(size_t)jc * DM + d] = f2bf(a.B.p[w][(size_t)d * ds + j]);
  } else if (bid < 7440) {                // prep_C (concat C^T rows, bf16)
    int idx = bid - 6416;
    int c = (idx & 3) * 256 + tid;
    int d = idx >> 2;
    if (c < DSUM) {
      int w, j;
      if (c < 64)       { w = 0; j = c; }
      else if (c < 192) { w = 1; j = c - 64; }
      else if (c < 448) { w = 2; j = c - 192; }
      else              { w = 3; j = c - 448; }
      a.Ct[(size_t)d * DSUM + c] = f2bf(a.C.p[w][(size_t)j * DM + d]);
    }
  } else if (bid < 9440) {                // transpose ow -> owT bf16
    int idx = bid - 7440;
    int n0 = (idx % 500) * 64, k0 = (idx / 500) * 64;
    int aa = tid >> 6, b = tid & 63;
    #pragma unroll
    for (int r = 0; r < 16; r++) {
      int k = r * 4 + aa;
      t[k][b] = a.ow[(size_t)(k0 + k) * VOCABN + n0 + b];
    }
    __syncthreads();
    #pragma unroll
    for (int r = 0; r < 16; r++) {
      int n = r * 4 + aa;
      a.owT[(size_t)(n0 + n) * DM + k0 + b] = f2bf(t[b][n]);
    }
  } else {                                // zero pad stripes of XA/XB (+ barrier counters)
    int b = bid - 9440;                   // 0..255; 16 blocks per chunk, 16 chunks
    if (b == 0 && tid < 2) a.syncp[tid] = 0;
    unsigned short* arrs[4] = {a.XAh, a.XAl, a.XBh, a.XBl};
    int chunk = b >> 4;                   // 0..15 : (array, batch)
    unsigned short* base = arrs[chunk >> 2] + (size_t)(chunk & 3) * 1536 * DSUM;
    uint4* p = (uint4*)base;              // 512*960 shorts = 61440 uint4 per chunk
    int start = (b & 15) * 3840;
    uint4 z = make_uint4(0, 0, 0, 0);
    for (int k = tid; k < 3840; k += 256) p[start + k] = z;
  }
}

// ---------------- split-bf16 128x128 GEMM tile (expm chain; split always on) ----------------

__device__ __forceinline__ void gemm_tile(
    const unsigned short* __restrict__ Ah, const unsigned short* __restrict__ Al,
    const unsigned short* __restrict__ Bth, const unsigned short* __restrict__ Btl,
    float* Cf, unsigned short* Ch, unsigned short* Cl,
    unsigned short* Th, unsigned short* Tl,
    int ds, int m0, int n0,
    unsigned short* As, unsigned short* Bs) {
  int tid = threadIdx.x;
  int wave = tid >> 6, lane = tid & 63;
  int wm = (wave >> 1) * 64, wn = (wave & 1) * 64;
  int q = lane >> 4, l15 = lane & 15;

  floatx4 acc[4][4];
  #pragma unroll
  for (int i = 0; i < 4; i++)
    #pragma unroll
    for (int j = 0; j < 4; j++)
      acc[i][j] = (floatx4){0.f, 0.f, 0.f, 0.f};

  for (int kt = 0; kt < ds; kt += 32) {
    __syncthreads();
    #pragma unroll
    for (int c0 = 0; c0 < 2; c0++) {
      int c = c0 * 256 + tid;
      int row = c >> 2, k8 = (c & 3) << 3;
      {
        int gr = m0 + row;
        uint4 hv = make_uint4(0, 0, 0, 0), lv = make_uint4(0, 0, 0, 0);
        if (gr < ds) {
          size_t idx = (size_t)gr * ds + kt + k8;
          hv = *(const uint4*)(Ah + idx);
          lv = *(const uint4*)(Al + idx);
        }
        *(uint4*)&As[(size_t)row * 40 + k8] = hv;
        *(uint4*)&As[(size_t)(128 + row) * 40 + k8] = lv;
      }
      {
        int gn = n0 + row;
        uint4 hv = make_uint4(0, 0, 0, 0), lv = make_uint4(0, 0, 0, 0);
        if (gn < ds) {
          size_t idx = (size_t)gn * ds + kt + k8;
          hv = *(const uint4*)(Bth + idx);
          lv = *(const uint4*)(Btl + idx);
        }
        *(uint4*)&Bs[(size_t)row * 40 + k8] = hv;
        *(uint4*)&Bs[(size_t)(128 + row) * 40 + k8] = lv;
      }
    }
    __syncthreads();
    short8 bh[4], bl[4];
    #pragma unroll
    for (int j = 0; j < 4; j++) {
      bh[j] = *(const short8*)&Bs[(size_t)(wn + j * 16 + l15) * 40 + q * 8];
      bl[j] = *(const short8*)&Bs[(size_t)(128 + wn + j * 16 + l15) * 40 + q * 8];
    }
    #pragma unroll
    for (int i = 0; i < 4; i++) {
      short8 ah = *(const short8*)&As[(size_t)(wm + i * 16 + l15) * 40 + q * 8];
      short8 al = *(const short8*)&As[(size_t)(128 + wm + i * 16 + l15) * 40 + q * 8];
      #pragma unroll
      for (int j = 0; j < 4; j++) {
        acc[i][j] = __builtin_amdgcn_mfma_f32_16x16x32_bf16(ah, bh[j], acc[i][j], 0, 0, 0);
        acc[i][j] = __builtin_amdgcn_mfma_f32_16x16x32_bf16(ah, bl[j], acc[i][j], 0, 0, 0);
        acc[i][j] = __builtin_amdgcn_mfma_f32_16x16x32_bf16(al, bh[j], acc[i][j], 0, 0, 0);
      }
    }
  }

  #pragma unroll
  for (int i = 0; i < 4; i++) {
    #pragma unroll
    for (int j = 0; j < 4; j++) {
      int col = n0 + wn + j * 16 + l15;
      if (col >= ds) continue;
      #pragma unroll
      for (int r = 0; r < 4; r++) {
        int row = m0 + wm + i * 16 + q * 4 + r;
        if (row >= ds) continue;
        float v = acc[i][j][r];
        size_t ci = (size_t)row * ds + col;
        if (Cf) Cf[ci] = v;
        if (Ch) {
          unsigned short h = f2bf(v);
          Ch[ci] = h;
          Cl[ci] = f2bf(v - bf2f(h));
        }
        if (Th) {
          size_t tix = (size_t)col * ds + row;
          unsigned short h = f2bf(v);
          Th[tix] = h;
          Tl[tix] = f2bf(v - bf2f(h));
        }
      }
    }
  }
}

// ---------------- dispatch 2: persistent expm chain (44 blocks) ----------------
// S0 mean partials | S1 P2 (+router on block 43) | S2 P3||P4 | S3 combine | S4.. 9 squarings

struct EArgs {
  const float* xef; float* meanp;
  const float *rw1, *rb1, *rw2, *rb2;
  Ptr4 A, D;
  float *w, *wD;
  const unsigned short *Mh, *Ml, *MTh, *MTl;
  float *P2f, *P3f, *P4f;
  unsigned short *P2h, *P2l, *P2Th, *P2Tl;
  unsigned short *Ph, *Pl, *PTh, *PTl;
  unsigned int* syncp;
};

__global__ __launch_bounds__(256) void k_expm_chain(EArgs a) {
  __shared__ __align__(16) unsigned short As[2 * 128 * 40];
  __shared__ __align__(16) unsigned short Bs[2 * 128 * 40];
  int bid = blockIdx.x, tid = threadIdx.x;
  const int dsw[4] = {64, 128, 256, 512};
  const size_t off2[4] = {0, 4096, 20480, 86016};

  // S0: mean partial sums (blocks 0..31: 8 per batch, 128 rows each)
  if (bid < 32) {
    int b = bid >> 3, t0 = (bid & 7) * 128;
    float s = 0.f;
    for (int t = 0; t < 128; t++) s += a.xef[((size_t)b * SEQ + t0 + t) * DM + tid];
    a.meanp[bid * DM + tid] = s;
  }
  gridbar(a.syncp, 44);

  // S1: P2 = M@M on blocks 0..21; router on block 43 (concurrent)
  if (bid < 22) {
    int w, tm, tn; tile22(bid, w, tm, tn);
    size_t o = off2[w];
    gemm_tile(a.Mh + o, a.Ml + o, a.MTh + o, a.MTl + o,
              a.P2f + o, a.P2h + o, a.P2l + o, a.P2Th + o, a.P2Tl + o,
              dsw[w], tm * 128, tn * 128, As, Bs);
  } else if (bid == 43) {
    float* m4  = (float*)As;            // [4][256]
    float* r1  = m4 + 4 * DM;           // [4][64]
    float* lg  = r1 + 4 * RHID;         // [16]
    float* wsh = lg + 16;               // [16]
    for (int b = 0; b < 4; b++) {
      float s = 0.f;
      for (int k = 0; k < 8; k++) s += a.meanp[(b * 8 + k) * DM + tid];
      m4[b * DM + tid] = s * (1.f / SEQ);
    }
    __syncthreads();
    {
      int b = tid >> 6, h = tid & 63;
      float s = a.rb1[h];
      for (int d0 = 0; d0 < DM; d0++) s += m4[b * DM + d0] * a.rw1[d0 * RHID + h];
      r1[b * RHID + h] = fmaxf(s, 0.f);
    }
    __syncthreads();
    if (tid < 16) {
      int bb = tid >> 2, i = tid & 3;
      float s2 = a.rb2[i];
      for (int hh = 0; hh < RHID; hh++) s2 += r1[bb * RHID + hh] * a.rw2[hh * 4 + i];
      lg[bb * 4 + i] = s2;
    }
    __syncthreads();
    if (tid < 4) {
      float m = lg[tid * 4 + 0];
      for (int i = 1; i < 4; i++) m = fmaxf(m, lg[tid * 4 + i]);
      float e[4], sum = 0.f;
      for (int i = 0; i < 4; i++) { e[i] = __expf(lg[tid * 4 + i] - m); sum += e[i]; }
      for (int i = 0; i < 4; i++) { wsh[tid * 4 + i] = e[i] / sum; a.w[tid * 4 + i] = wsh[tid * 4 + i]; }
    }
    __syncthreads();
    for (int bb = 0; bb < 4; bb++) {
      float v = 0.f;
      for (int i = 0; i < 4; i++) v += wsh[bb * 4 + i] * a.D.p[i][tid];
      a.wD[bb * DM + tid] = v;
    }
  }
  gridbar(a.syncp, 44);

  // S2: P3 = P2@M (blocks 0..21) and P4 = P2@P2 (blocks 22..43)
  if (bid < 22) {
    int w, tm, tn; tile22(bid, w, tm, tn);
    size_t o = off2[w];
    gemm_tile(a.P2h + o, a.P2l + o, a.MTh + o, a.MTl + o,
              a.P3f + o, nullptr, nullptr, nullptr, nullptr,
              dsw[w], tm * 128, tn * 128, As, Bs);
  } else {
    int w, tm, tn; tile22(bid - 22, w, tm, tn);
    size_t o = off2[w];
    gemm_tile(a.P2h + o, a.P2l + o, a.P2Th + o, a.P2Tl + o,
              a.P4f + o, nullptr, nullptr, nullptr, nullptr,
              dsw[w], tm * 128, tn * 128, As, Bs);
  }
  gridbar(a.syncp, 44);

  // S3: combine -> power slot 0 (Ad)
  {
    int gt = bid * 256 + tid;
    for (int id = gt; id < SZ2; id += 44 * 256) {
      int w, e; world_from_id(id, w, e);
      int s = 6 + w, ds = 64 << w;
      int i = e >> s, j = e & (ds - 1);
      float v = ((i == j) ? 1.f : 0.f) + 0.1f * a.A.p[w][e]
              + 0.5f * a.P2f[id] + (1.f / 6.f) * a.P3f[id] + (1.f / 24.f) * a.P4f[id];
      unsigned short h = f2bf(v);
      unsigned short l = f2bf(v - bf2f(h));
      a.Ph[id] = h; a.Pl[id] = l;
      int tix = (id - e) + (j << s) + i;
      a.PTh[tix] = h; a.PTl[tix] = l;
    }
  }
  gridbar(a.syncp, 44);

  // S4..S12: squaring chain, slots 1..9
  for (int j = 1; j < 10; j++) {
    if (bid < 22) {
      int w, tm, tn; tile22(bid, w, tm, tn);
      size_t so = (size_t)(j - 1) * SZ2 + off2[w];
      size_t dd = (size_t)j * SZ2 + off2[w];
      gemm_tile(a.Ph + so, a.Pl + so, a.PTh + so, a.PTl + so,
                nullptr, a.Ph + dd, a.Pl + dd, a.PTh + dd, a.PTl + dd,
                dsw[w], tm * 128, tn * 128, As, Bs);
    }
    if (j < 9) gridbar(a.syncp, 44);
  }
}

// ---------------- X-GEMM stage (U projection / Kogge-Stone round) ----------------
// m97 structure: unpadded LDS [128][32], global_load_lds width-16 staging.

template<int SPLIT, int KS>
__device__ __forceinline__ void xstage(
    const unsigned short* __restrict__ Ah, const unsigned short* __restrict__ Al,
    const unsigned short* __restrict__ Bth, const unsigned short* __restrict__ Btl,
    unsigned short* Ch, unsigned short* Cl,
    unsigned short* Hc, int hcoff, const float* wcol,
    int N, int K, int lda, int ldbt, int shift,
    int m0, int n0, unsigned short* As, unsigned short* Bs) {
  int prow0 = ((m0 >> 10) * 1536) + 512 + (m0 & 1023);   // padded out-row base
  int arow0 = KS ? (prow0 - shift) : m0;

  int tid = threadIdx.x;
  int wave = tid >> 6, lane = tid & 63;
  int wm = (wave >> 1) * 64, wn = (wave & 1) * 64;
  int q = lane >> 4, l15 = lane & 15;
  int srow = lane >> 2, scol = (lane & 3) * 8;

  floatx4 acc[4][4];
  #pragma unroll
  for (int i = 0; i < 4; i++)
    #pragma unroll
    for (int j = 0; j < 4; j++)
      acc[i][j] = (floatx4){0.f, 0.f, 0.f, 0.f};

  for (int kt = 0; kt < K; kt += 32) {
    int ar = arow0 + wave * 32 + srow;
    int br = n0 + wave * 32 + srow;
    const unsigned short* ag = Ah + (size_t)ar * lda + kt + scol;
    const unsigned short* bg = Bth + (size_t)br * ldbt + kt + scol;
    size_t as16 = (size_t)16 * lda, bs16 = (size_t)16 * ldbt;
    unsigned short* al0 = &As[wave * 1024];
    unsigned short* bl0 = &Bs[wave * 1024];
    gll16(ag, al0);        gll16(ag + as16, al0 + 512);
    gll16(bg, bl0);        gll16(bg + bs16, bl0 + 512);
    if (SPLIT) {
      const unsigned short* ag2 = Al + (size_t)ar * lda + kt + scol;
      const unsigned short* bg2 = Btl + (size_t)br * ldbt + kt + scol;
      gll16(ag2, al0 + 4096); gll16(ag2 + as16, al0 + 4096 + 512);
      gll16(bg2, bl0 + 4096); gll16(bg2 + bs16, bl0 + 4096 + 512);
    }
    __syncthreads();
    short8 bh[4], bl[4];
    #pragma unroll
    for (int j = 0; j < 4; j++)
      bh[j] = *(const short8*)&Bs[(wn + j * 16 + l15) * 32 + q * 8];
    if (SPLIT) {
      #pragma unroll
      for (int j = 0; j < 4; j++)
        bl[j] = *(const short8*)&Bs[4096 + (wn + j * 16 + l15) * 32 + q * 8];
    }
    #pragma unroll
    for (int i = 0; i < 4; i++) {
      short8 ah = *(const short8*)&As[(wm + i * 16 + l15) * 32 + q * 8];
      #pragma unroll
      for (int j = 0; j < 4; j++)
        acc[i][j] = __builtin_amdgcn_mfma_f32_16x16x32_bf16(ah, bh[j], acc[i][j], 0, 0, 0);
      if (SPLIT) {
        short8 al = *(const short8*)&As[4096 + (wm + i * 16 + l15) * 32 + q * 8];
        #pragma unroll
        for (int j = 0; j < 4; j++) {
          acc[i][j] = __builtin_amdgcn_mfma_f32_16x16x32_bf16(ah, bl[j], acc[i][j], 0, 0, 0);
          acc[i][j] = __builtin_amdgcn_mfma_f32_16x16x32_bf16(al, bh[j], acc[i][j], 0, 0, 0);
        }
      }
    }
    __syncthreads();
  }

  #pragma unroll
  for (int j = 0; j < 4; j++) {
    int col = n0 + wn + j * 16 + l15;
    if (col >= N) continue;
    #pragma unroll
    for (int i = 0; i < 4; i++) {
      #pragma unroll
      for (int r = 0; r < 4; r++) {
        int rr = wm + i * 16 + q * 4 + r;
        size_t oi = (size_t)(prow0 + rr) * N + col;
        float v = acc[i][j][r];
        if (KS) v += bf2f(Ah[oi]) + bf2f(Al[oi]);
        unsigned short h = f2bf(v);
        Ch[oi] = h;
        Cl[oi] = f2bf(v - bf2f(h));
        if (KS && Hc) {
          int grow = m0 + rr;
          Hc[(size_t)grow * DSUM + hcoff + col] = f2bf(v * wcol[(m0 >> 10) * 4]);
        }
      }
    }
  }
}

// ---------------- fused H_cat @ C_cat tile + op epilogue (K=960, no split) ----------------

__device__ __forceinline__ void cct_tile(
    const unsigned short* __restrict__ Hc, const unsigned short* __restrict__ Ct,
    const float* __restrict__ xef, const float* __restrict__ wD,
    unsigned short* __restrict__ op,
    int m0, int n0, unsigned short* As, unsigned short* Bs) {
  int tid = threadIdx.x;
  int wave = tid >> 6, lane = tid & 63;
  int wm = (wave >> 1) * 64, wn = (wave & 1) * 64;
  int q = lane >> 4, l15 = lane & 15;
  int srow = lane >> 2, scol = (lane & 3) * 8;

  floatx4 acc[4][4];
  #pragma unroll
  for (int i = 0; i < 4; i++)
    #pragma unroll
    for (int j = 0; j < 4; j++)
      acc[i][j] = (floatx4){0.f, 0.f, 0.f, 0.f};

  for (int kt = 0; kt < DSUM; kt += 32) {
    const unsigned short* ag = Hc + (size_t)(m0 + wave * 32 + srow) * DSUM + kt + scol;
    const unsigned short* bg = Ct + (size_t)(n0 + wave * 32 + srow) * DSUM + kt + scol;
    unsigned short* al0 = &As[wave * 1024];
    unsigned short* bl0 = &Bs[wave * 1024];
    gll16(ag, al0); gll16(ag + 16 * DSUM, al0 + 512);
    gll16(bg, bl0); gll16(bg + 16 * DSUM, bl0 + 512);
    __syncthreads();
    short8 bh[4];
    #pragma unroll
    for (int j = 0; j < 4; j++)
      bh[j] = *(const short8*)&Bs[(wn + j * 16 + l15) * 32 + q * 8];
    #pragma unroll
    for (int i = 0; i < 4; i++) {
      short8 ah = *(const short8*)&As[(wm + i * 16 + l15) * 32 + q * 8];
      #pragma unroll
      for (int j = 0; j < 4; j++)
        acc[i][j] = __builtin_amdgcn_mfma_f32_16x16x32_bf16(ah, bh[j], acc[i][j], 0, 0, 0);
    }
    __syncthreads();
  }

  #pragma unroll
  for (int j = 0; j < 4; j++) {
    int col = n0 + wn + j * 16 + l15;
    #pragma unroll
    for (int i = 0; i < 4; i++) {
      #pragma unroll
      for (int r = 0; r < 4; r++) {
        int row = m0 + wm + i * 16 + q * 4 + r;
        size_t oi = (size_t)row * DM + col;
        op[oi] = f2bf(acc[i][j][r] + xef[oi] * wD[(size_t)(row >> 10) * DM + col]);
      }
    }
  }
}

// ---------------- dispatch 3: persistent scan chain (256 blocks) ----------------
// U = xe@B_w -> 10 Kogge-Stone rounds -> fused op = bf16(H@C + xe*wD)

struct SArgs {
  const unsigned short *xebf, *Bt;
  unsigned short *XAh, *XAl, *XBh, *XBl;
  const unsigned short *PTh, *PTl;
  unsigned short* Hc;
  const float* w;
  const unsigned short* Ct;
  const float *xef, *wD;
  unsigned short* op;
  unsigned int* syncp;
};

__global__ __launch_bounds__(256) void k_scan_chain(SArgs a) {
  __shared__ __align__(16) unsigned short As[2 * 4096];
  __shared__ __align__(16) unsigned short Bs[2 * 4096];
  int t = blockIdx.x;
  int w, tm, tn; tile256(t, w, tm, tn);
  const int dsw[4] = {64, 128, 256, 512};
  const size_t off2[4] = {0, 4096, 20480, 86016};
  const int offc[4] = {0, 64, 192, 448};
  const size_t wxoff[4] = {0, (size_t)XROWS * 64, (size_t)XROWS * 192, (size_t)XROWS * 448};
  int ds = dsw[w];

  // U stage: xe @ B_w into padded buffer A
  xstage<0, 0>(a.xebf, nullptr, a.Bt + (size_t)offc[w] * DM, nullptr,
               a.XAh + wxoff[w], a.XAl + wxoff[w],
               nullptr, 0, nullptr,
               ds, DM, DM, DM, 0, tm * 128, tn * 128, As, Bs);
  gridbar(a.syncp, 256);

  // 10 Kogge-Stone rounds
  unsigned short *xh = a.XAh, *xl = a.XAl, *yh = a.XBh, *yl = a.XBl;
  for (int j = 0; j < 10; j++) {
    xstage<1, 1>(xh + wxoff[w], xl + wxoff[w],
                 a.PTh + (size_t)j * SZ2 + off2[w], a.PTl + (size_t)j * SZ2 + off2[w],
                 yh + wxoff[w], yl + wxoff[w],
                 (j == 9) ? a.Hc : nullptr, offc[w], a.w + w,
                 ds, ds, ds, ds, 1 << j, tm * 128, tn * 128, As, Bs);
    gridbar(a.syncp, 256);
    unsigned short* t1 = xh; xh = yh; yh = t1;
    unsigned short* t2 = xl; xl = yl; yl = t2;
  }

  // fused op = bf16(Hc@Ct + xe*wD) on blocks 0..63 (K=960, no split-K, no atomics)
  if (t < 64) cct_tile(a.Hc, a.Ct, a.xef, a.wD, a.op, (t >> 1) * 128, (t & 1) * 128, As, Bs);
}

// ---------------- dispatch 4: final projection [4096,256]@[256,32000] + bias ----------------

__global__ __launch_bounds__(256) void gemm_big(const unsigned short* __restrict__ A,
                                                const unsigned short* __restrict__ B,
                                                const float* __restrict__ bias,
                                                float* __restrict__ out) {
  int bx = blockIdx.x;                  // 8000; m-fastest so 32-consecutive share the B tile
  int tm = bx & 31, tn = bx >> 5;
  int m0 = tm * 128, n0 = tn * 128;

  __shared__ __align__(16) unsigned short As[4096], Bs[4096];
  int tid = threadIdx.x;
  int wave = tid >> 6, lane = tid & 63;
  int wm = (wave >> 1) * 64, wn = (wave & 1) * 64;
  int q = lane >> 4, l15 = lane & 15;
  int srow = lane >> 2, scol = (lane & 3) * 8;

  floatx4 acc[4][4];
  #pragma unroll
  for (int i = 0; i < 4; i++)
    #pragma unroll
    for (int j = 0; j < 4; j++)
      acc[i][j] = (floatx4){0.f, 0.f, 0.f, 0.f};

  for (int kt = 0; kt < DM; kt += 32) {
    const unsigned short* ag = A + (size_t)(m0 + wave * 32 + srow) * DM + kt + scol;
    const unsigned short* bg = B + (size_t)(n0 + wave * 32 + srow) * DM + kt + scol;
    unsigned short* al0 = &As[wave * 32 * 32];
    unsigned short* bl0 = &Bs[wave * 32 * 32];
    gll16(ag, al0); gll16(ag + 16 * DM, al0 + 512);
    gll16(bg, bl0); gll16(bg + 16 * DM, bl0 + 512);
    __syncthreads();
    short8 bh[4];
    #pragma unroll
    for (int j = 0; j < 4; j++)
      bh[j] = *(const short8*)&Bs[(wn + j * 16 + l15) * 32 + q * 8];
    #pragma unroll
    for (int i = 0; i < 4; i++) {
      short8 ah = *(const short8*)&As[(wm + i * 16 + l15) * 32 + q * 8];
      #pragma unroll
      for (int j = 0; j < 4; j++)
        acc[i][j] = __builtin_amdgcn_mfma_f32_16x16x32_bf16(ah, bh[j], acc[i][j], 0, 0, 0);
    }
    __syncthreads();
  }

  #pragma unroll
  for (int j = 0; j < 4; j++) {
    int col = n0 + wn + j * 16 + l15;
    float bj = bias[col];
    #pragma unroll
    for (int i = 0; i < 4; i++) {
      #pragma unroll
      for (int r = 0; r < 4; r++) {
        int row = m0 + wm + i * 16 + q * 4 + r;
        out[(size_t)row * VOCABN + col] = acc[i][j][r] + bj;
      }
    }
  }
}

// ---------------- host ----------------

extern "C" void kernel_launch(void* const* d_in, const int* in_sizes, int n_in,
                              void* d_out, int out_size, void* d_ws, size_t ws_size,
                              hipStream_t stream) {
  const int*   x   = (const int*)d_in[0];
  const float* emb = (const float*)d_in[1];
  Ptr4 Aw = {{(const float*)d_in[2], (const float*)d_in[6], (const float*)d_in[10], (const float*)d_in[14]}};
  Ptr4 Bw = {{(const float*)d_in[3], (const float*)d_in[7], (const float*)d_in[11], (const float*)d_in[15]}};
  Ptr4 Cw = {{(const float*)d_in[4], (const float*)d_in[8], (const float*)d_in[12], (const float*)d_in[16]}};
  Ptr4 Dw = {{(const float*)d_in[5], (const float*)d_in[9], (const float*)d_in[13], (const float*)d_in[17]}};
  const float* rw1 = (const float*)d_in[18];
  const float* rb1 = (const float*)d_in[19];
  const float* rw2 = (const float*)d_in[20];
  const float* rb2 = (const float*)d_in[21];
  const float* ow  = (const float*)d_in[22];
  const float* ob  = (const float*)d_in[23];
  float* out = (float*)d_out;

  char* wsb = (char*)d_ws;
  size_t off = 0;
  auto alloc = [&](size_t bytes) { size_t o = off; off = (off + bytes + 255) & ~(size_t)255; return o; };

  size_t o_xef   = alloc((size_t)NTOK * DM * 4);
  size_t o_xebf  = alloc((size_t)NTOK * DM * 2);
  size_t o_meanp = alloc((size_t)32 * DM * 4);
  size_t o_w     = alloc(64);
  size_t o_wD    = alloc(4 * DM * 4);
  size_t o_sync  = alloc(256);
  size_t o_Mh   = alloc((size_t)SZ2 * 2), o_Ml = alloc((size_t)SZ2 * 2);
  size_t o_MTh  = alloc((size_t)SZ2 * 2), o_MTl = alloc((size_t)SZ2 * 2);
  size_t o_P2f  = alloc((size_t)SZ2 * 4);
  size_t o_P2h  = alloc((size_t)SZ2 * 2), o_P2l = alloc((size_t)SZ2 * 2);
  size_t o_P2Th = alloc((size_t)SZ2 * 2), o_P2Tl = alloc((size_t)SZ2 * 2);
  size_t o_P3f  = alloc((size_t)SZ2 * 4);
  size_t o_P4f  = alloc((size_t)SZ2 * 4);
  size_t o_Ph   = alloc((size_t)10 * SZ2 * 2), o_Pl  = alloc((size_t)10 * SZ2 * 2);
  size_t o_PTh  = alloc((size_t)10 * SZ2 * 2), o_PTl = alloc((size_t)10 * SZ2 * 2);
  size_t o_XAh  = alloc((size_t)XPADE * 2);
  size_t o_XAl  = alloc((size_t)XPADE * 2);
  size_t o_XBh  = alloc((size_t)XPADE * 2);
  size_t o_XBl  = alloc((size_t)XPADE * 2);
  size_t o_Hc   = alloc((size_t)NTOK * DSUM * 2);
  size_t o_op   = alloc((size_t)NTOK * DM * 2);
  size_t o_Bt   = alloc((size_t)DSUM * DM * 2);
  size_t o_Ct   = alloc((size_t)DM * DSUM * 2);
  size_t o_owT  = alloc((size_t)VOCABN * DM * 2);

  auto U16 = [&](size_t o) { return (unsigned short*)(wsb + o); };
  auto F32 = [&](size_t o) { return (float*)(wsb + o); };

  // 1. fused setup: embed + all preps + pad zeroing + barrier-counter reset
  SetupArgs sa;
  sa.x = x; sa.emb = emb; sa.xef = F32(o_xef); sa.xebf = U16(o_xebf);
  sa.A = Aw; sa.B = Bw; sa.C = Cw; sa.ow = ow;
  sa.Mh = U16(o_Mh); sa.Ml = U16(o_Ml); sa.MTh = U16(o_MTh); sa.MTl = U16(o_MTl);
  sa.Bt = U16(o_Bt); sa.Ct = U16(o_Ct); sa.owT = U16(o_owT);
  sa.XAh = U16(o_XAh); sa.XAl = U16(o_XAl); sa.XBh = U16(o_XBh); sa.XBl = U16(o_XBl);
  sa.syncp = (unsigned int*)(wsb + o_sync);
  k_setup<<<9696, 256, 0, stream>>>(sa);

  // 2. persistent expm chain: mean/router + Taylor + combine + 9 squarings
  EArgs ea;
  ea.xef = F32(o_xef); ea.meanp = F32(o_meanp);
  ea.rw1 = rw1; ea.rb1 = rb1; ea.rw2 = rw2; ea.rb2 = rb2;
  ea.A = Aw; ea.D = Dw;
  ea.w = F32(o_w); ea.wD = F32(o_wD);
  ea.Mh = U16(o_Mh); ea.Ml = U16(o_Ml); ea.MTh = U16(o_MTh); ea.MTl = U16(o_MTl);
  ea.P2f = F32(o_P2f); ea.P3f = F32(o_P3f); ea.P4f = F32(o_P4f);
  ea.P2h = U16(o_P2h); ea.P2l = U16(o_P2l); ea.P2Th = U16(o_P2Th); ea.P2Tl = U16(o_P2Tl);
  ea.Ph = U16(o_Ph); ea.Pl = U16(o_Pl); ea.PTh = U16(o_PTh); ea.PTl = U16(o_PTl);
  ea.syncp = (unsigned int*)(wsb + o_sync) + 0;
  k_expm_chain<<<44, 256, 0, stream>>>(ea);

  // 3. persistent scan chain: U + 10 KS rounds + fused op
  SArgs sc;
  sc.xebf = U16(o_xebf); sc.Bt = U16(o_Bt);
  sc.XAh = U16(o_XAh); sc.XAl = U16(o_XAl); sc.XBh = U16(o_XBh); sc.XBl = U16(o_XBl);
  sc.PTh = U16(o_PTh); sc.PTl = U16(o_PTl);
  sc.Hc = U16(o_Hc); sc.w = F32(o_w);
  sc.Ct = U16(o_Ct); sc.xef = F32(o_xef); sc.wD = F32(o_wD); sc.op = U16(o_op);
  sc.syncp = (unsigned int*)(wsb + o_sync) + 1;
  k_scan_chain<<<256, 256, 0, stream>>>(sc);

  // 4. out = op @ ow + ob
  gemm_big<<<8000, 256, 0, stream>>>(U16(o_op), U16(o_owT), ob, out);

  (void)in_sizes; (void)n_in; (void)out_size; (void)ws_size;
}